// Round 3
// baseline (1888.676 us; speedup 1.0000x reference)
//
#include <hip/hip_runtime.h>
#include <hip/hip_bf16.h>

typedef unsigned short u16;

#define NTOK 40001
#define NPAD 40064
#define PADZ 63
#define LCH  313
#define SIDE 200

__device__ __forceinline__ float bf2f(u16 u){ return __uint_as_float(((unsigned)u)<<16); }
__device__ __forceinline__ u16 f2bf(float f){
  unsigned x = __float_as_uint(f);
  unsigned r = (x + 0x7FFFu + ((x >> 16) & 1u)) >> 16;
  return (u16)r;
}

// ---------------- cls row ----------------
__global__ void k_cls(const float* __restrict__ cls, float* __restrict__ h){
  h[threadIdx.x] = cls[threadIdx.x];
}

// ---------------- generic zero ----------------
__global__ void k_zero(float* __restrict__ p, int n){
  int i = blockIdx.x*256 + threadIdx.x;
  if (i < n) p[i] = 0.f;
}

// ---------------- fc1: h[1..40000] = relu(x @ W + b) ----------------
// grid 625, block 256. BM=64, BN=256(full), BK=32.
__global__ __launch_bounds__(256) void k_fc1(const float* __restrict__ X, const float* __restrict__ W,
                                             const float* __restrict__ B, float* __restrict__ h){
  __shared__ float As[32][68];
  __shared__ float Bs[32][256];
  int tid = threadIdx.x;
  int tx = tid & 15, ty = tid >> 4;
  int r0 = blockIdx.x * 64;
  float acc[4][16];
  #pragma unroll
  for (int i=0;i<4;i++)
    #pragma unroll
    for (int j=0;j<16;j++) acc[i][j]=0.f;
  for (int k0=0;k0<1024;k0+=32){
    #pragma unroll
    for (int rep=0;rep<2;rep++){
      int i = tid + rep*256;
      int r = i >> 3, k4 = (i & 7)*4;
      float4 v = *(const float4*)(X + (size_t)(r0 + r)*1024 + k0 + k4);
      As[k4+0][r] = v.x; As[k4+1][r] = v.y;
      As[k4+2][r] = v.z; As[k4+3][r] = v.w;
    }
    #pragma unroll
    for (int rep=0;rep<8;rep++){
      int i = tid + rep*256;
      int k = i >> 6, c4 = (i & 63)*4;
      float4 f = *(const float4*)(W + (size_t)(k0 + k)*256 + c4);
      *(float4*)&Bs[k][c4] = f;
    }
    __syncthreads();
    #pragma unroll
    for (int k=0;k<32;k++){
      float4 a = *(const float4*)&As[k][ty*4];
      float av[4] = {a.x,a.y,a.z,a.w};
      #pragma unroll
      for (int g=0; g<4; g++){
        float4 b = *(const float4*)&Bs[k][g*64 + tx*4];
        float bv[4] = {b.x,b.y,b.z,b.w};
        #pragma unroll
        for (int i=0;i<4;i++)
          #pragma unroll
          for (int j=0;j<4;j++) acc[i][g*4+j] += av[i]*bv[j];
      }
    }
    __syncthreads();
  }
  #pragma unroll
  for (int i=0;i<4;i++){
    int r = r0 + ty*4 + i;
    float* hp = h + (size_t)(1 + r)*256;
    #pragma unroll
    for (int g=0; g<4; g++){
      int c = g*64 + tx*4;
      float4 bb = *(const float4*)(B + c);
      float4 o;
      o.x = fmaxf(acc[i][g*4+0] + bb.x, 0.f);
      o.y = fmaxf(acc[i][g*4+1] + bb.y, 0.f);
      o.z = fmaxf(acc[i][g*4+2] + bb.z, 0.f);
      o.w = fmaxf(acc[i][g*4+3] + bb.w, 0.f);
      *(float4*)(hp + c) = o;
    }
  }
}

// ---------------- fused LN + qkv gemm: (40064 x 256) @ (256 x 384), q-cols scaled ----
// grid (626,3), block 256. BM=64 BN=128 BK=32. Row p<63 => zero input (pad AFTER LN).
__global__ __launch_bounds__(256) void k_qkv(const float* __restrict__ H,
                                             const float* __restrict__ g, const float* __restrict__ b,
                                             const float* __restrict__ W, float* __restrict__ QKV){
  __shared__ float As[32][68];
  __shared__ float Bs[32][128];
  __shared__ float mus[64], rss[64];
  __shared__ float gs[256], bs2[256];
  int tid = threadIdx.x;
  int tx = tid & 15, ty = tid >> 4;
  int r0 = blockIdx.x * 64;
  int c0 = blockIdx.y * 128;
  gs[tid]  = g[tid];
  bs2[tid] = b[tid];
  { // per-row LN stats: 4 threads per row, shfl-combine
    int r = tid >> 2, q = tid & 3;
    int p = r0 + r;
    float s = 0.f, sq = 0.f;
    if (p >= PADZ){
      const float* row = H + (size_t)(p - PADZ)*256 + q*64;
      #pragma unroll
      for (int j=0;j<64;j+=4){
        float4 x = *(const float4*)(row + j);
        s  += x.x+x.y+x.z+x.w;
        sq += x.x*x.x+x.y*x.y+x.z*x.z+x.w*x.w;
      }
    }
    s += __shfl_xor(s,1); sq += __shfl_xor(sq,1);
    s += __shfl_xor(s,2); sq += __shfl_xor(sq,2);
    if (q == 0){
      float mu = s*(1.f/256.f);
      float var = sq*(1.f/256.f) - mu*mu;
      mus[r] = mu;
      rss[r] = rsqrtf(fmaxf(var, 0.f) + 1e-5f);
    }
  }
  __syncthreads();
  float acc[4][8];
  #pragma unroll
  for (int i=0;i<4;i++)
    #pragma unroll
    for (int j=0;j<8;j++) acc[i][j]=0.f;
  for (int k0=0;k0<256;k0+=32){
    #pragma unroll
    for (int rep=0;rep<2;rep++){
      int i = tid + rep*256;
      int r = i >> 3, k4 = (i & 7)*4;
      int p = r0 + r;
      float4 v; v.x=0.f; v.y=0.f; v.z=0.f; v.w=0.f;
      if (p >= PADZ){
        float4 x = *(const float4*)(H + (size_t)(p - PADZ)*256 + k0 + k4);
        float mu = mus[r], rs = rss[r];
        v.x = (x.x-mu)*rs*gs[k0+k4+0] + bs2[k0+k4+0];
        v.y = (x.y-mu)*rs*gs[k0+k4+1] + bs2[k0+k4+1];
        v.z = (x.z-mu)*rs*gs[k0+k4+2] + bs2[k0+k4+2];
        v.w = (x.w-mu)*rs*gs[k0+k4+3] + bs2[k0+k4+3];
      }
      As[k4+0][r]=v.x; As[k4+1][r]=v.y; As[k4+2][r]=v.z; As[k4+3][r]=v.w;
    }
    #pragma unroll
    for (int rep=0;rep<4;rep++){
      int i = tid + rep*256;
      int k = i >> 5, c4 = (i & 31)*4;
      float4 f = *(const float4*)(W + (size_t)(k0 + k)*384 + c0 + c4);
      *(float4*)&Bs[k][c4] = f;
    }
    __syncthreads();
    #pragma unroll
    for (int k=0;k<32;k++){
      float4 a = *(const float4*)&As[k][ty*4];
      float av[4] = {a.x,a.y,a.z,a.w};
      #pragma unroll
      for (int g2=0; g2<2; g2++){
        float4 b2 = *(const float4*)&Bs[k][g2*64 + tx*4];
        float bv[4] = {b2.x,b2.y,b2.z,b2.w};
        #pragma unroll
        for (int i=0;i<4;i++)
          #pragma unroll
          for (int j=0;j<4;j++) acc[i][g2*4+j] += av[i]*bv[j];
      }
    }
    __syncthreads();
  }
  float scale = (blockIdx.y == 0) ? 0.17677669529663687f : 1.f; // q tile only
  #pragma unroll
  for (int i=0;i<4;i++){
    int p = r0 + ty*4 + i;
    float* o = QKV + (size_t)p*384 + c0;
    #pragma unroll
    for (int g2=0; g2<2; g2++){
      int c = g2*64 + tx*4;
      float4 st;
      st.x = acc[i][g2*4+0]*scale; st.y = acc[i][g2*4+1]*scale;
      st.z = acc[i][g2*4+2]*scale; st.w = acc[i][g2*4+3]*scale;
      *(float4*)(o + c) = st;
    }
  }
}

// ---------------- landmark means (atomic partial sums) ----------------
// grid (128, 8), block 256 (cols 0..255 = q|k). QL/KL zeroed beforehand.
__global__ __launch_bounds__(256) void k_land(const float* __restrict__ QKV, float* __restrict__ QL,
                                              float* __restrict__ KL){
  int i = blockIdx.x, tc = blockIdx.y;
  int c = threadIdx.x;
  int t0 = tc*40;
  int nt = LCH - t0; if (nt > 40) nt = 40;
  const float* p = QKV + ((size_t)i*LCH + t0)*384 + c;
  float s0=0.f,s1=0.f,s2=0.f,s3=0.f;
  int t = 0;
  for (; t+4 <= nt; t += 4){
    s0 += p[(size_t)(t+0)*384];
    s1 += p[(size_t)(t+1)*384];
    s2 += p[(size_t)(t+2)*384];
    s3 += p[(size_t)(t+3)*384];
  }
  for (; t < nt; t++) s0 += p[(size_t)t*384];
  float s = ((s0+s1)+(s2+s3)) * (1.f/313.f);
  int hd = (c >> 5) & 3, d = c & 31;
  if (c < 128) atomicAdd(&QL[hd*4096 + i*32 + d], s);
  else         atomicAdd(&KL[hd*4096 + i*32 + d], s);
}

// ---------------- sim2 + row softmax -> A2 ----------------
__global__ __launch_bounds__(128) void k_sim2(const float* __restrict__ QL, const float* __restrict__ KL,
                                              float* __restrict__ A2){
  int h = blockIdx.y, i = blockIdx.x, j = threadIdx.x;
  __shared__ float q[32];
  __shared__ float red[2], red2[2];
  if (j < 32) q[j] = QL[h*4096 + i*32 + j];
  __syncthreads();
  const float* kr = KL + h*4096 + j*32;
  float s = 0.f;
  #pragma unroll
  for (int d=0;d<32;d++) s += q[d]*kr[d];
  float m = s;
  #pragma unroll
  for (int off=32; off; off>>=1) m = fmaxf(m, __shfl_xor(m, off));
  if ((j & 63) == 0) red[j>>6] = m;
  __syncthreads();
  m = fmaxf(red[0], red[1]);
  float p = __expf(fmaxf(s - m, -80.f));
  float sum = p;
  #pragma unroll
  for (int off=32; off; off>>=1) sum += __shfl_xor(sum, off);
  if ((j & 63) == 0) red2[j>>6] = sum;
  __syncthreads();
  sum = red2[0] + red2[1];
  A2[h*16384 + i*128 + j] = p / fmaxf(sum, 1e-30f);
}

// ---------------- scalar s = max(rowsum)*max(colsum) over all heads ----------------
__global__ __launch_bounds__(512) void k_colmax(const float* __restrict__ A2, float* __restrict__ S){
  int t = threadIdx.x;
  int h = t >> 7, j = t & 127;
  const float* base = A2 + h*16384;
  float cs = 0.f, rs = 0.f;
  #pragma unroll 4
  for (int i=0;i<128;i++){ cs += base[i*128 + j]; rs += base[j*128 + i]; }
  __shared__ float mc[8], mr[8];
  float c = cs, r = rs;
  #pragma unroll
  for (int off=32; off; off>>=1){ c = fmaxf(c, __shfl_xor(c,off)); r = fmaxf(r, __shfl_xor(r,off)); }
  int w = t >> 6;
  if ((t & 63) == 0){ mc[w] = c; mr[w] = r; }
  __syncthreads();
  if (t == 0){
    float M1 = mc[0], M2 = mr[0];
    for (int k=1;k<8;k++){ M1 = fmaxf(M1, mc[k]); M2 = fmaxf(M2, mr[k]); }
    S[0] = M1 * M2;
  }
}

// ---------------- z0 = A2^T / s ----------------
__global__ void k_z0(const float* __restrict__ A2, const float* __restrict__ S, float* __restrict__ Z){
  int idx = blockIdx.x*256 + threadIdx.x;
  float inv = 1.f / fmaxf(S[0], 1e-30f);
  int h = idx >> 14, rem = idx & 16383, i = rem >> 7, j = rem & 127;
  Z[h*16384 + j*128 + i] = A2[idx] * inv;
}

// ---------------- batched 128x128: C[h] = alpha*A[h]@B[h] + beta*A[h] ----------------
// grid (16,4): r0=(x&7)*16, cb=(x>>3)*64. Output clamped (NaN-scrub diagnostic).
__global__ __launch_bounds__(256) void k_bmm(const float* __restrict__ A, const float* __restrict__ B,
                                             float* __restrict__ C, float alpha, float beta){
  __shared__ float As[16][132];
  __shared__ float Bs[128][64];
  int h = blockIdx.y;
  int r0 = (blockIdx.x & 7) * 16, cb = (blockIdx.x >> 3) * 64;
  const float* Ah = A + h*16384;
  const float* Bh = B + h*16384;
  int tid = threadIdx.x;
  #pragma unroll
  for (int rep=0;rep<8;rep++){
    int i = tid + rep*256;
    int r = i >> 7, k = i & 127;
    As[r][k] = Ah[(r0 + r)*128 + k];
  }
  #pragma unroll
  for (int rep=0;rep<32;rep++){
    int i = tid + rep*256;
    int k = i >> 6, c = i & 63;
    Bs[k][c] = Bh[k*128 + cb + c];
  }
  __syncthreads();
  int r = tid >> 4, c0 = (tid & 15) * 4;
  float4 acc; acc.x=0.f; acc.y=0.f; acc.z=0.f; acc.w=0.f;
  for (int k4=0;k4<128;k4+=4){
    float4 a = *(const float4*)&As[r][k4];
    float aa[4] = {a.x,a.y,a.z,a.w};
    #pragma unroll
    for (int kk=0;kk<4;kk++){
      float4 b = *(const float4*)&Bs[k4+kk][c0];
      acc.x += aa[kk]*b.x; acc.y += aa[kk]*b.y; acc.z += aa[kk]*b.z; acc.w += aa[kk]*b.w;
    }
  }
  float4 av = *(const float4*)&As[r][cb + c0];
  float4 o;
  o.x = fminf(fmaxf(alpha*acc.x + beta*av.x, -1e20f), 1e20f);
  o.y = fminf(fmaxf(alpha*acc.y + beta*av.y, -1e20f), 1e20f);
  o.z = fminf(fmaxf(alpha*acc.z + beta*av.z, -1e20f), 1e20f);
  o.w = fminf(fmaxf(alpha*acc.w + beta*av.w, -1e20f), 1e20f);
  *(float4*)(C + h*16384 + (r0 + r)*128 + cb + c0) = o;
}

// ---------------- max squared norms for softmax bound ----------------
__global__ __launch_bounds__(256) void k_normk(const float* __restrict__ QKV, float* __restrict__ KN2){
  int tid = threadIdx.x;
  int row = blockIdx.x*64 + (tid >> 2);
  int h = tid & 3;
  const float* v = QKV + (size_t)row*384 + 128 + h*32;
  float n2 = 0.f;
  #pragma unroll
  for (int d=0;d<32;d+=4){ float4 x = *(const float4*)(v+d); n2 += x.x*x.x+x.y*x.y+x.z*x.z+x.w*x.w; }
  #pragma unroll
  for (int off=4; off<64; off<<=1) n2 = fmaxf(n2, __shfl_xor(n2, off));
  __shared__ float red[4][4];
  int lane = tid & 63, w = tid >> 6;
  if (lane < 4) red[w][lane] = n2;
  __syncthreads();
  if (tid < 4){
    float m = fmaxf(fmaxf(red[0][tid], red[1][tid]), fmaxf(red[2][tid], red[3][tid]));
    atomicMax((unsigned*)&KN2[tid], __float_as_uint(m));
  }
}

__global__ __launch_bounds__(256) void k_normq(const float* __restrict__ QL, float* __restrict__ QN2){
  int tid = threadIdx.x;
  #pragma unroll
  for (int rep=0; rep<2; rep++){
    int row = tid + rep*256;
    int h = row >> 7;
    const float* q = QL + row*32;
    float n2 = 0.f;
    #pragma unroll
    for (int d=0;d<32;d+=4){ float4 x = *(const float4*)(q+d); n2 += x.x*x.x+x.y*x.y+x.z*x.z+x.w*x.w; }
    atomicMax((unsigned*)&QN2[h], __float_as_uint(n2));
  }
}

// ---------------- flash sim3: per-chunk exp(QL.K^T - bound) @ V partials ----------------
// grid (313,4), block 256. 128 keys per chunk. Writes LPART / OPART (no atomics).
__global__ __launch_bounds__(256) void k_flash(const float* __restrict__ QKV, const float* __restrict__ QL,
                                               const float* __restrict__ KN2, const float* __restrict__ QN2,
                                               float* __restrict__ LPART, float* __restrict__ OPART){
  __shared__ union UU {
    struct { float Qt[32][132]; float Kt[32][132]; } a;
    u16 PsT[128][132];
  } U;
  __shared__ float Vs[128][36];
  int h = blockIdx.y, ci = blockIdx.x;
  int k0 = ci * 128;
  int tid = threadIdx.x;
  int tx = tid & 15, ty = tid >> 4;
  #pragma unroll
  for (int rep=0;rep<16;rep++){
    int i = tid + rep*256;
    int q = i >> 5, d = i & 31;
    U.a.Qt[d][q] = QL[h*4096 + i];
  }
  #pragma unroll
  for (int rep=0;rep<16;rep++){
    int i = tid + rep*256;
    int kk = i >> 5, d = i & 31;
    U.a.Kt[d][kk] = QKV[(size_t)(k0+kk)*384 + 128 + h*32 + d];
    Vs[kk][d]     = QKV[(size_t)(k0+kk)*384 + 256 + h*32 + d];
  }
  __syncthreads();
  float bound = sqrtf(KN2[h]*QN2[h]) + 1e-6f;
  float s[8][8];
  #pragma unroll
  for (int i=0;i<8;i++)
    #pragma unroll
    for (int c=0;c<8;c++) s[i][c]=0.f;
  for (int d=0;d<32;d++){
    float4 qa = *(const float4*)&U.a.Qt[d][ty*8];
    float4 qb = *(const float4*)&U.a.Qt[d][ty*8+4];
    float4 ka = *(const float4*)&U.a.Kt[d][tx*8];
    float4 kb = *(const float4*)&U.a.Kt[d][tx*8+4];
    float qv[8] = {qa.x,qa.y,qa.z,qa.w,qb.x,qb.y,qb.z,qb.w};
    float kv[8] = {ka.x,ka.y,ka.z,ka.w,kb.x,kb.y,kb.z,kb.w};
    #pragma unroll
    for (int i=0;i<8;i++)
      #pragma unroll
      for (int c=0;c<8;c++) s[i][c] += qv[i]*kv[c];
  }
  float l[8];
  #pragma unroll
  for (int i=0;i<8;i++){
    float li = 0.f;
    #pragma unroll
    for (int c=0;c<8;c++){ s[i][c] = __expf(fmaxf(s[i][c] - bound, -80.f)); li += s[i][c]; }
    l[i] = li;
  }
  #pragma unroll
  for (int off=1; off<16; off<<=1)
    #pragma unroll
    for (int i=0;i<8;i++) l[i] += __shfl_xor(l[i], off);
  if (tx == 0){
    #pragma unroll
    for (int i=0;i<8;i++) LPART[(size_t)(h*313 + ci)*128 + ty*8 + i] = l[i];
  }
  __syncthreads();
  #pragma unroll
  for (int i=0;i<8;i++)
    #pragma unroll
    for (int c=0;c<8;c++) U.PsT[tx*8+c][ty*8+i] = f2bf(s[i][c]);
  __syncthreads();
  int txp = tx & 7, kh = (tx >> 3)*64;
  float o[8][4];
  #pragma unroll
  for (int i=0;i<8;i++)
    #pragma unroll
    for (int c=0;c<4;c++) o[i][c]=0.f;
  for (int k=0;k<64;k++){
    const u16* pr = &U.PsT[kh + k][ty*8];
    ushort4 pa = *(const ushort4*)pr;
    ushort4 pb = *(const ushort4*)(pr+4);
    float4 vv = *(const float4*)&Vs[kh + k][txp*4];
    float pv[8] = {bf2f(pa.x),bf2f(pa.y),bf2f(pa.z),bf2f(pa.w),
                   bf2f(pb.x),bf2f(pb.y),bf2f(pb.z),bf2f(pb.w)};
    float vd[4] = {vv.x,vv.y,vv.z,vv.w};
    #pragma unroll
    for (int i=0;i<8;i++)
      #pragma unroll
      for (int c=0;c<4;c++) o[i][c] += pv[i]*vd[c];
  }
  #pragma unroll
  for (int i=0;i<8;i++)
    #pragma unroll
    for (int c=0;c<4;c++) o[i][c] += __shfl_xor(o[i][c], 8);
  if (tx < 8){
    size_t base = ((size_t)(h*313 + ci)*128)*32;
    #pragma unroll
    for (int i=0;i<8;i++){
      float4 st; st.x=o[i][0]; st.y=o[i][1]; st.z=o[i][2]; st.w=o[i][3];
      *(float4*)(OPART + base + (size_t)(ty*8+i)*32 + txp*4) = st;
    }
  }
}

// ---------------- reduce flash partials ----------------
__global__ __launch_bounds__(256) void k_fred(const float* __restrict__ OPART, float* __restrict__ ACC){
  int h = blockIdx.y;
  int off = blockIdx.x*256 + threadIdx.x; // 0..4095
  const float* p = OPART + (size_t)h*1282048 + off;
  float s0=0.f,s1=0.f,s2=0.f,s3=0.f;
  int ci=0;
  for (; ci+4<=313; ci+=4){
    s0 += p[(size_t)(ci+0)*4096];
    s1 += p[(size_t)(ci+1)*4096];
    s2 += p[(size_t)(ci+2)*4096];
    s3 += p[(size_t)(ci+3)*4096];
  }
  for (; ci<313; ci++) s0 += p[(size_t)ci*4096];
  ACC[h*4096 + off] = (s0+s1)+(s2+s3);
}

__global__ void k_lred(const float* __restrict__ LPART, float* __restrict__ LAC){
  int idx = blockIdx.x*256 + threadIdx.x; // 0..511
  int h = idx >> 7, j = idx & 127;
  const float* p = LPART + (size_t)(h*313)*128 + j;
  float s0=0.f,s1=0.f;
  int ci=0;
  for (; ci+2<=313; ci+=2){ s0 += p[(size_t)(ci+0)*128]; s1 += p[(size_t)(ci+1)*128]; }
  for (; ci<313; ci++) s0 += p[(size_t)ci*128];
  LAC[idx] = s0+s1;
}

// ---------------- W = Z @ t3  (t3 = ACC / LAC) ----------------
__global__ __launch_bounds__(256) void k_w(const float* __restrict__ Z, const float* __restrict__ ACC,
                                           const float* __restrict__ LAC, float* __restrict__ WB){
  int h = blockIdx.x;
  __shared__ float t3s[128][33];
  int tid = threadIdx.x;
  #pragma unroll
  for (int rep=0; rep<16; rep++){
    int i = tid + rep*256;
    int j = i >> 5, d = i & 31;
    float t3 = ACC[h*4096 + i] / fmaxf(LAC[h*128 + j], 1e-30f);
    t3s[j][d] = fminf(fmaxf(t3, -1e20f), 1e20f);
  }
  __syncthreads();
  int i = tid >> 1, dh = (tid & 1)*16;
  float acc[16];
  #pragma unroll
  for (int d=0;d<16;d++) acc[d]=0.f;
  const float* zr = Z + h*16384 + i*128;
  for (int j=0;j<128;j++){
    float zv = zr[j];
    #pragma unroll
    for (int d=0;d<16;d++) acc[d] += zv * t3s[j][dh + d];
  }
  float* w = WB + h*4096 + i*32 + dh;
  #pragma unroll
  for (int d=0;d<16;d+=4){
    float4 st;
    st.x = fminf(fmaxf(acc[d+0], -1e20f), 1e20f);
    st.y = fminf(fmaxf(acc[d+1], -1e20f), 1e20f);
    st.z = fminf(fmaxf(acc[d+2], -1e20f), 1e20f);
    st.w = fminf(fmaxf(acc[d+3], -1e20f), 1e20f);
    *(float4*)(w+d) = st;
  }
}

// ---------------- sim1: OH = softmax(Q KL^T) @ W  (64 tokens / block) ----------------
// grid (626,4), block 256.
__global__ __launch_bounds__(256) void k_sim1(const float* __restrict__ QKV, const float* __restrict__ KL,
                                              const float* __restrict__ WB, float* __restrict__ OH){
  __shared__ union UU {
    struct { float Qt[32][68]; float KLt[32][132]; } a;
    float PsT[128][68];
  } U;
  __shared__ float ws[128][36];
  int h = blockIdx.y;
  int p0 = blockIdx.x * 64;
  int tid = threadIdx.x;
  int tx = tid & 15, ty = tid >> 4;
  #pragma unroll
  for (int rep=0;rep<8;rep++){
    int i = tid + rep*256;
    int t = i >> 5, d = i & 31;
    U.a.Qt[d][t] = QKV[(size_t)(p0 + t)*384 + h*32 + d];
  }
  #pragma unroll
  for (int rep=0;rep<16;rep++){
    int i = tid + rep*256;
    int j = i >> 5, d = i & 31;
    U.a.KLt[d][j] = KL[h*4096 + i];
    ws[j][d] = WB[h*4096 + i];
  }
  __syncthreads();
  float s[4][8];
  #pragma unroll
  for (int i=0;i<4;i++)
    #pragma unroll
    for (int c=0;c<8;c++) s[i][c]=0.f;
  for (int d=0;d<32;d++){
    float4 qa = *(const float4*)&U.a.Qt[d][ty*4];
    float4 ka = *(const float4*)&U.a.KLt[d][tx*4];
    float4 kb = *(const float4*)&U.a.KLt[d][64 + tx*4];
    float qv[4] = {qa.x,qa.y,qa.z,qa.w};
    float kv[8] = {ka.x,ka.y,ka.z,ka.w,kb.x,kb.y,kb.z,kb.w};
    #pragma unroll
    for (int i=0;i<4;i++)
      #pragma unroll
      for (int c=0;c<8;c++) s[i][c] += qv[i]*kv[c];
  }
  // row softmax over 128 cols (16 tx lanes x 8 cols)
  float m[4], l[4];
  #pragma unroll
  for (int i=0;i<4;i++){
    float mi = s[i][0];
    #pragma unroll
    for (int c=1;c<8;c++) mi = fmaxf(mi, s[i][c]);
    m[i] = mi;
  }
  #pragma unroll
  for (int off=1; off<16; off<<=1)
    #pragma unroll
    for (int i=0;i<4;i++) m[i] = fmaxf(m[i], __shfl_xor(m[i], off));
  #pragma unroll
  for (int i=0;i<4;i++){
    float li = 0.f;
    #pragma unroll
    for (int c=0;c<8;c++){ s[i][c] = __expf(fmaxf(s[i][c] - m[i], -80.f)); li += s[i][c]; }
    l[i] = li;
  }
  #pragma unroll
  for (int off=1; off<16; off<<=1)
    #pragma unroll
    for (int i=0;i<4;i++) l[i] += __shfl_xor(l[i], off);
  #pragma unroll
  for (int i=0;i<4;i++){
    float inv = 1.f / fmaxf(l[i], 1e-30f);
    #pragma unroll
    for (int c=0;c<8;c++) s[i][c] *= inv;
  }
  __syncthreads();
  #pragma unroll
  for (int i=0;i<4;i++)
    #pragma unroll
    for (int c=0;c<8;c++){
      int j = (c>>2)*64 + tx*4 + (c&3);
      U.PsT[j][ty*4 + i] = s[i][c];
    }
  __syncthreads();
  int txp = tx & 7, jh = (tx >> 3)*64;
  float o[4][4];
  #pragma unroll
  for (int i=0;i<4;i++)
    #pragma unroll
    for (int c=0;c<4;c++) o[i][c]=0.f;
  for (int j=0;j<64;j++){
    float4 pv = *(const float4*)&U.PsT[jh + j][ty*4];
    float4 wv = *(const float4*)&ws[jh + j][txp*4];
    float pa[4] = {pv.x,pv.y,pv.z,pv.w};
    float wa[4] = {wv.x,wv.y,wv.z,wv.w};
    #pragma unroll
    for (int i=0;i<4;i++)
      #pragma unroll
      for (int c=0;c<4;c++) o[i][c] += pa[i]*wa[c];
  }
  #pragma unroll
  for (int i=0;i<4;i++)
    #pragma unroll
    for (int c=0;c<4;c++) o[i][c] += __shfl_xor(o[i][c], 8);
  if (tx < 8){
    #pragma unroll
    for (int i=0;i<4;i++){
      float4 st; st.x=o[i][0]; st.y=o[i][1]; st.z=o[i][2]; st.w=o[i][3];
      *(float4*)(OH + (size_t)(p0 + ty*4 + i)*128 + h*32 + txp*4) = st;
    }
  }
}

// ---------------- depthwise 33x1 conv residual on V, added into OH ----------------
__global__ __launch_bounds__(256) void k_res(const float* __restrict__ QKV, const float* __restrict__ RK,
                                             float* __restrict__ OH){
  __shared__ float vs[96][128];
  __shared__ float rks[132];
  int p0 = blockIdx.x * 64;
  int tid = threadIdx.x;
  #pragma unroll
  for (int rep=0;rep<48;rep++){
    int i = tid + rep*256;
    int lr = i >> 7, c = i & 127;
    int row = p0 - 16 + lr;
    float v = 0.f;
    if (row >= 0 && row < NPAD) v = QKV[(size_t)row*384 + 256 + c];
    vs[lr][c] = v;
  }
  if (tid < 132) rks[tid] = RK[tid];
  __syncthreads();
  int c = tid & 127, rb = (tid >> 7)*32;
  int hh = c >> 5;
  const float* rk = &rks[hh*33];
  for (int k=0;k<32;k++){
    int r = rb + k;
    float acc = 0.f;
    #pragma unroll
    for (int t=0;t<33;t++) acc += vs[r + t][c] * rk[t];
    OH[(size_t)(p0 + r)*128 + c] += acc;
  }
}

// ---------------- out-proj: h += OH @ out_w + out_b  (rows >= 63 only) ----------------
// grid (626,2), block 256.
__global__ __launch_bounds__(256) void k_proj(const float* __restrict__ OH, const float* __restrict__ W,
                                              const float* __restrict__ B, float* __restrict__ h){
  __shared__ float As[32][68];
  __shared__ float Bs[32][128];
  int tid = threadIdx.x;
  int tx = tid & 15, ty = tid >> 4;
  int r0 = blockIdx.x * 64, c0 = blockIdx.y * 128;
  float acc[4][8];
  #pragma unroll
  for (int i=0;i<4;i++)
    #pragma unroll
    for (int j=0;j<8;j++) acc[i][j]=0.f;
  for (int k0=0;k0<128;k0+=32){
    #pragma unroll
    for (int rep=0;rep<2;rep++){
      int i = tid + rep*256;
      int r = i >> 3, k4 = (i & 7)*4;
      float4 v = *(const float4*)(OH + (size_t)(r0 + r)*128 + k0 + k4);
      As[k4+0][r]=v.x; As[k4+1][r]=v.y; As[k4+2][r]=v.z; As[k4+3][r]=v.w;
    }
    #pragma unroll
    for (int rep=0;rep<4;rep++){
      int i = tid + rep*256;
      int k = i >> 5, c4 = (i & 31)*4;
      float4 f = *(const float4*)(W + (size_t)(k0 + k)*256 + c0 + c4);
      *(float4*)&Bs[k][c4] = f;
    }
    __syncthreads();
    #pragma unroll
    for (int k=0;k<32;k++){
      float4 a = *(const float4*)&As[k][ty*4];
      float av[4] = {a.x,a.y,a.z,a.w};
      #pragma unroll
      for (int g=0; g<2; g++){
        float4 b = *(const float4*)&Bs[k][g*64 + tx*4];
        float bv[4] = {b.x,b.y,b.z,b.w};
        #pragma unroll
        for (int i=0;i<4;i++)
          #pragma unroll
          for (int j=0;j<4;j++) acc[i][g*4+j] += av[i]*bv[j];
      }
    }
    __syncthreads();
  }
  #pragma unroll
  for (int i=0;i<4;i++){
    int p = r0 + ty*4 + i;
    if (p >= PADZ){
      float* hp = h + (size_t)(p - PADZ)*256 + c0;
      #pragma unroll
      for (int g=0; g<2; g++){
        int c = g*64 + tx*4;
        float4 bb = *(const float4*)(B + c0 + c);
        float4 cur = *(float4*)(hp + c);
        cur.x += acc[i][g*4+0] + bb.x;
        cur.y += acc[i][g*4+1] + bb.y;
        cur.z += acc[i][g*4+2] + bb.z;
        cur.w += acc[i][g*4+3] + bb.w;
        *(float4*)(hp + c) = cur;
      }
    }
  }
}

// ---------------- depthwise 7x7+5x5+3x3 convs: out = img + c7+b7 + c5+b5 + c3+b3 ----------------
// grid (25,25,8), block 256. 8x8 px tile x 32 channels.
__global__ __launch_bounds__(256) void k_dw(const float* __restrict__ h,
                                            const float* __restrict__ W7, const float* __restrict__ B7,
                                            const float* __restrict__ W5, const float* __restrict__ B5,
                                            const float* __restrict__ W3, const float* __restrict__ B3,
                                            float* __restrict__ out){
  __shared__ float img[196][32];
  __shared__ float w7s[49][32], w5s[25][32], w3s[9][32];
  __shared__ float bs[32];
  int bx = blockIdx.x, by = blockIdx.y;
  int c0 = blockIdx.z * 32;
  int tid = threadIdx.x;
  int gx0 = bx*8 - 3, gy0 = by*8 - 3;
  for (int rep=0; rep<25; rep++){
    int i = tid + rep*256;
    if (i < 6272){
      int pos = i >> 5, c = i & 31;
      int ly = pos / 14, lx = pos - ly*14;
      int gy = gy0 + ly, gx = gx0 + lx;
      float v = 0.f;
      if (gy >= 0 && gy < SIDE && gx >= 0 && gx < SIDE)
        v = h[(size_t)(1 + gy*SIDE + gx)*256 + c0 + c];
      img[pos][c] = v;
    }
  }
  for (int rep=0; rep<7; rep++){
    int i = tid + rep*256;
    if (i < 1568){ int t = i >> 5, c = i & 31; w7s[t][c] = W7[(size_t)(c0 + c)*49 + t]; }
  }
  for (int rep=0; rep<4; rep++){
    int i = tid + rep*256;
    if (i < 800){ int t = i >> 5, c = i & 31; w5s[t][c] = W5[(size_t)(c0 + c)*25 + t]; }
  }
  for (int rep=0; rep<2; rep++){
    int i = tid + rep*256;
    if (i < 288){ int t = i >> 5, c = i & 31; w3s[t][c] = W3[(size_t)(c0 + c)*9 + t]; }
  }
  if (tid < 32) bs[tid] = B7[c0+tid] + B5[c0+tid] + B3[c0+tid];
  __syncthreads();
  int c = tid & 31, pg = tid >> 5;
  float acc[8];
  #pragma unroll
  for (int px=0; px<8; px++) acc[px] = img[(pg+3)*14 + px+3][c] + bs[c];
  for (int t=0;t<49;t++){
    float wv = w7s[t][c];
    int dy = t/7, dx = t - dy*7;
    #pragma unroll
    for (int px=0;px<8;px++) acc[px] += img[(pg+dy)*14 + px+dx][c]*wv;
  }
  for (int t=0;t<25;t++){
    float wv = w5s[t][c];
    int dy = t/5, dx = t - dy*5;
    #pragma unroll
    for (int px=0;px<8;px++) acc[px] += img[(pg+1+dy)*14 + px+1+dx][c]*wv;
  }
  for (int t=0;t<9;t++){
    float wv = w3s[t][c];
    int dy = t/3, dx = t - dy*3;
    #pragma unroll
    for (int px=0;px<8;px++) acc[px] += img[(pg+2+dy)*14 + px+2+dx][c]*wv;
  }
  int gy = by*8 + pg;
  #pragma unroll
  for (int px=0;px<8;px++){
    int gxp = bx*8 + px;
    out[(size_t)(gy*SIDE + gxp)*256 + c0 + c] = acc[px];
  }
}

__global__ void k_copyback(const float* __restrict__ temp, float* __restrict__ h){
  int i = blockIdx.x*256 + threadIdx.x; // 2,560,000 float4
  float4 v = ((const float4*)temp)[i];
  ((float4*)(h + 256))[i] = v;
}

// ---------------- final LN(row0) @ fc2 + b ----------------
__global__ __launch_bounds__(256) void k_final(const float* __restrict__ h, const float* __restrict__ g,
                                               const float* __restrict__ b, const float* __restrict__ W2,
                                               const float* __restrict__ B2, float* __restrict__ out){
  __shared__ float red[4], red2[4];
  __shared__ float hn[256];
  int tid = threadIdx.x;
  float x = h[tid];
  float s = x, sq = x*x;
  #pragma unroll
  for (int off=32; off; off>>=1){ s += __shfl_xor(s,off); sq += __shfl_xor(sq,off); }
  int w = tid >> 6;
  if ((tid & 63) == 0){ red[w] = s; red2[w] = sq; }
  __syncthreads();
  s = red[0]+red[1]+red[2]+red[3];
  sq = red2[0]+red2[1]+red2[2]+red2[3];
  float mu = s*(1.f/256.f);
  float var = sq*(1.f/256.f) - mu*mu;
  float rstd = rsqrtf(fmaxf(var, 0.f) + 1e-5f);
  hn[tid] = (x - mu)*rstd*g[tid] + b[tid];
  __syncthreads();
  if (tid < 4){
    float acc = B2[tid];
    for (int c=0;c<256;c++) acc += hn[c]*W2[c*4 + tid];
    out[tid] = acc;
  }
}

// ================= host side =================
struct Bufs {
  float *HB, *QKV, *OH, *LP, *QL, *KL, *WB, *A2, *ZB0, *ZB1, *PB, *T1B, *T2B, *SB, *KN2, *QN2, *LAC, *ACC;
};

static void attention(const Bufs& B, const float* qkv_w, const float* out_w, const float* out_b,
                      const float* res_k, const float* ln_g, const float* ln_b, hipStream_t stream){
  k_qkv<<<dim3(626,3),256,0,stream>>>(B.HB, ln_g, ln_b, qkv_w, B.QKV);
  k_zero<<<128,256,0,stream>>>(B.QL, 32768);            // QL + KL contiguous
  k_land<<<dim3(128,8),256,0,stream>>>(B.QKV, B.QL, B.KL);
  k_sim2<<<dim3(128,4),128,0,stream>>>(B.QL, B.KL, B.A2);
  k_colmax<<<1,512,0,stream>>>(B.A2, B.SB);
  k_z0<<<256,256,0,stream>>>(B.A2, B.SB, B.ZB0);
  float* zin = B.ZB0; float* zout = B.ZB1;
  for (int it=0; it<6; it++){
    k_bmm<<<dim3(16,4),256,0,stream>>>(B.A2, zin, B.PB, 1.f, 0.f);     // P = X@Z
    k_bmm<<<dim3(16,4),256,0,stream>>>(B.PB, B.PB, B.T1B, -1.f, 7.f);  // T1 = 7P - P@P
    k_bmm<<<dim3(16,4),256,0,stream>>>(B.PB, B.T1B, B.T2B, -1.f, 15.f);// T2 = 15P - P@T1
    k_bmm<<<dim3(16,4),256,0,stream>>>(zin, B.T2B, zout, -0.25f, 3.25f);// Z' = 3.25Z - 0.25 Z@T2
    float* t = zin; zin = zout; zout = t;
  }
  k_zero<<<1,256,0,stream>>>(B.KN2, 8);                 // KN2 + QN2
  k_normk<<<626,256,0,stream>>>(B.QKV, B.KN2);
  k_normq<<<1,256,0,stream>>>(B.QL, B.QN2);
  // OPART aliases OH (overwritten later by sim1)
  k_flash<<<dim3(313,4),256,0,stream>>>(B.QKV, B.QL, B.KN2, B.QN2, B.LP, B.OH);
  k_fred<<<dim3(16,4),256,0,stream>>>(B.OH, B.ACC);
  k_lred<<<2,256,0,stream>>>(B.LP, B.LAC);
  k_w<<<4,256,0,stream>>>(zin, B.ACC, B.LAC, B.WB);
  k_sim1<<<dim3(626,4),256,0,stream>>>(B.QKV, B.KL, B.WB, B.OH);
  k_res<<<626,256,0,stream>>>(B.QKV, res_k, B.OH);
  k_proj<<<dim3(626,2),256,0,stream>>>(B.OH, out_w, out_b, B.HB);
}

extern "C" void kernel_launch(void* const* d_in, const int* in_sizes, int n_in,
                              void* d_out, int out_size, void* d_ws, size_t ws_size,
                              hipStream_t stream){
  (void)in_sizes; (void)n_in; (void)out_size; (void)ws_size;
  const float* x_path = (const float*)d_in[0];
  const float* fc1_w  = (const float*)d_in[1];
  const float* fc1_b  = (const float*)d_in[2];
  const float* cls    = (const float*)d_in[3];
  const float* ln1_g  = (const float*)d_in[4];
  const float* ln1_b  = (const float*)d_in[5];
  const float* qkv1_w = (const float*)d_in[6];
  const float* out1_w = (const float*)d_in[7];
  const float* out1_b = (const float*)d_in[8];
  const float* res1_k = (const float*)d_in[9];
  const float* p7_w = (const float*)d_in[10];
  const float* p7_b = (const float*)d_in[11];
  const float* p5_w = (const float*)d_in[12];
  const float* p5_b = (const float*)d_in[13];
  const float* p3_w = (const float*)d_in[14];
  const float* p3_b = (const float*)d_in[15];
  const float* ln2_g  = (const float*)d_in[16];
  const float* ln2_b  = (const float*)d_in[17];
  const float* qkv2_w = (const float*)d_in[18];
  const float* out2_w = (const float*)d_in[19];
  const float* out2_b = (const float*)d_in[20];
  const float* res2_k = (const float*)d_in[21];
  const float* lnf_g  = (const float*)d_in[22];
  const float* lnf_b  = (const float*)d_in[23];
  const float* fc2_w  = (const float*)d_in[24];
  const float* fc2_b  = (const float*)d_in[25];

  // Layout: small amplification-sensitive buffers FIRST, big tiles after. ~119.7 MiB
  float* ws = (float*)d_ws;
  Bufs B;
  B.QL  = ws;                       // 16,384
  B.KL  = B.QL  + 16384;            // 16,384
  B.WB  = B.KL  + 16384;            // 16,384
  B.A2  = B.WB  + 16384;            // 65,536
  B.ZB0 = B.A2  + 65536;            // 65,536
  B.ZB1 = B.ZB0 + 65536;            // 65,536
  B.PB  = B.ZB1 + 65536;            // 65,536
  B.T1B = B.PB  + 65536;            // 65,536
  B.T2B = B.T1B + 65536;            // 65,536
  B.SB  = B.T2B + 65536;            // 16
  B.KN2 = B.SB  + 16;               // 4
  B.QN2 = B.KN2 + 4;                // 4
  B.LAC = B.QN2 + 4;                // 512
  B.ACC = B.LAC + 512;              // 16,384
  B.LP  = B.ACC + 16384;            // 160,256 (4*313*128)
  B.OH  = B.LP  + 160256;           // 5,128,192 (40064 x 128; aliases OPART)
  B.HB  = B.OH  + 5128192;          // 10,240,256 (40001 x 256)
  B.QKV = B.HB  + 10240256;         // 15,384,576 (40064 x 384; aliases dwconv temp)

  k_cls<<<1,256,0,stream>>>(cls, B.HB);
  k_fc1<<<625,256,0,stream>>>(x_path, fc1_w, fc1_b, B.HB);

  attention(B, qkv1_w, out1_w, out1_b, res1_k, ln1_g, ln1_b, stream);

  // dwconv temp aliases QKV (dead between attentions)
  k_dw<<<dim3(25,25,8),256,0,stream>>>(B.HB, p7_w,p7_b, p5_w,p5_b, p3_w,p3_b, B.QKV);
  k_copyback<<<10000,256,0,stream>>>(B.QKV, B.HB);

  attention(B, qkv2_w, out2_w, out2_b, res2_k, ln2_g, ln2_b, stream);

  k_final<<<1,256,0,stream>>>(B.HB, lnf_g, lnf_b, fc2_w, fc2_b, (float*)d_out);
}

// Round 4
// 1509.146 us; speedup vs baseline: 1.2515x; 1.2515x over previous
//
#include <hip/hip_runtime.h>
#include <hip/hip_bf16.h>

typedef unsigned short u16;
typedef __attribute__((ext_vector_type(8))) short short8;
typedef __attribute__((ext_vector_type(4))) float floatx4;

#define NTOK 40001
#define NPAD 40064
#define PADZ 63
#define LCH  313
#define SIDE 200

__device__ __forceinline__ float bf2f(u16 u){ return __uint_as_float(((unsigned)u)<<16); }
__device__ __forceinline__ u16 f2bf(float f){
  unsigned x = __float_as_uint(f);
  unsigned r = (x + 0x7FFFu + ((x >> 16) & 1u)) >> 16;
  return (u16)r;
}

// ---------------- cls row ----------------
__global__ void k_cls(const float* __restrict__ cls, float* __restrict__ h){
  h[threadIdx.x] = cls[threadIdx.x];
}

// ---------------- generic zero ----------------
__global__ void k_zero(float* __restrict__ p, int n){
  int i = blockIdx.x*256 + threadIdx.x;
  if (i < n) p[i] = 0.f;
}

// ---------------- weight transpose+bf16: Wt[n][k] = bf16(W[k][n]) ----------------
__global__ void k_transp(const float* __restrict__ W, u16* __restrict__ Wt, int K, int N){
  int idx = blockIdx.x*256 + threadIdx.x;
  if (idx >= K*N) return;
  int k = idx / N, n = idx - k*N;
  Wt[(size_t)n*K + k] = f2bf(W[idx]);
}

// ================= MFMA GEMM kernels: BM=128 BN=128 BK=32, 4 waves 2x2 =================
// LDS: As/Bs [128][40] u16 (pad 8 shorts -> 80B row stride: 2-way bank alias = free)
// frag layouts (verified m89/m120): A lane m=l&15,k=q*8+j ; B lane n=l&15,k=q*8+j ;
// D col=l&15, row=q*4+reg.

// ---------------- fc1: h[1+r] = relu(X @ W + b), X 40000x1024 ----------------
__global__ __launch_bounds__(256) void k_fc1m(const float* __restrict__ X, const u16* __restrict__ WT,
                                              const float* __restrict__ Bias, float* __restrict__ h){
  __shared__ __align__(16) u16 As[128*40];
  __shared__ __align__(16) u16 Bs[128*40];
  int tid = threadIdx.x;
  int r0 = blockIdx.x*128, c0 = blockIdx.y*128;
  int wid = tid>>6, lane = tid&63, lm = lane&15, q = lane>>4;
  int wr = wid>>1, wc = wid&1;
  floatx4 acc[4][4];
  #pragma unroll
  for (int i=0;i<4;i++)
    #pragma unroll
    for (int j=0;j<4;j++) acc[i][j] = (floatx4){0.f,0.f,0.f,0.f};
  for (int k0=0;k0<1024;k0+=32){
    #pragma unroll
    for (int rep=0;rep<4;rep++){
      int idx = tid + rep*256;
      int row = idx>>3, k4 = (idx&7)*4;
      int gr = r0 + row;
      float4 v; v.x=0.f;v.y=0.f;v.z=0.f;v.w=0.f;
      if (gr < 40000) v = *(const float4*)(X + (size_t)gr*1024 + k0 + k4);
      ushort4 st; st.x=f2bf(v.x); st.y=f2bf(v.y); st.z=f2bf(v.z); st.w=f2bf(v.w);
      *(ushort4*)&As[row*40 + k4] = st;
    }
    #pragma unroll
    for (int rep=0;rep<2;rep++){
      int idx = tid + rep*256;
      int n = idx>>2, k8 = (idx&3)*8;
      uint4 wv = *(const uint4*)(WT + (size_t)(c0+n)*1024 + k0 + k8);
      *(uint4*)&Bs[n*40 + k8] = wv;
    }
    __syncthreads();
    short8 af[4], bfr[4];
    #pragma unroll
    for (int i=0;i<4;i++) af[i]  = *(const short8*)&As[(wr*64 + i*16 + lm)*40 + q*8];
    #pragma unroll
    for (int j=0;j<4;j++) bfr[j] = *(const short8*)&Bs[(wc*64 + j*16 + lm)*40 + q*8];
    #pragma unroll
    for (int i=0;i<4;i++)
      #pragma unroll
      for (int j=0;j<4;j++)
        acc[i][j] = __builtin_amdgcn_mfma_f32_16x16x32_bf16(af[i], bfr[j], acc[i][j], 0,0,0);
    __syncthreads();
  }
  #pragma unroll
  for (int j=0;j<4;j++){
    int col = c0 + wc*64 + j*16 + lm;
    float bj = Bias[col];
    #pragma unroll
    for (int i=0;i<4;i++)
      #pragma unroll
      for (int reg=0;reg<4;reg++){
        int row = r0 + wr*64 + i*16 + q*4 + reg;
        if (row < 40000)
          h[(size_t)(1+row)*256 + col] = fmaxf(acc[i][j][reg] + bj, 0.f);
      }
  }
}

// ---------------- fused LN + qkv: QKV = LN(H,pad) @ W, q-scaled ----------------
// grid (313,3). Rows p<63 are zeros (pad AFTER LN).
__global__ __launch_bounds__(256) void k_qkvm(const float* __restrict__ H,
                                              const float* __restrict__ g, const float* __restrict__ b,
                                              const u16* __restrict__ WT, float* __restrict__ QKV){
  __shared__ __align__(16) u16 As[128*40];
  __shared__ __align__(16) u16 Bs[128*40];
  __shared__ float mus[128], rss[128];
  __shared__ float gs[256], bs2[256];
  int tid = threadIdx.x;
  int r0 = blockIdx.x*128, c0 = blockIdx.y*128;
  int wid = tid>>6, lane = tid&63, lm = lane&15, q = lane>>4;
  int wr = wid>>1, wc = wid&1;
  gs[tid] = g[tid]; bs2[tid] = b[tid];
  { // LN stats: 2 threads per row
    int r = tid>>1, hv = tid&1;
    int p = r0 + r;
    float s=0.f, sq=0.f;
    if (p >= PADZ){
      const float* row = H + (size_t)(p - PADZ)*256 + hv*128;
      #pragma unroll
      for (int j=0;j<128;j+=4){
        float4 x = *(const float4*)(row + j);
        s  += x.x+x.y+x.z+x.w;
        sq += x.x*x.x+x.y*x.y+x.z*x.z+x.w*x.w;
      }
    }
    s += __shfl_xor(s,1); sq += __shfl_xor(sq,1);
    if (hv == 0){
      float mu = s*(1.f/256.f);
      float var = sq*(1.f/256.f) - mu*mu;
      mus[r] = mu;
      rss[r] = rsqrtf(fmaxf(var, 0.f) + 1e-5f);
    }
  }
  __syncthreads();
  floatx4 acc[4][4];
  #pragma unroll
  for (int i=0;i<4;i++)
    #pragma unroll
    for (int j=0;j<4;j++) acc[i][j] = (floatx4){0.f,0.f,0.f,0.f};
  for (int k0=0;k0<256;k0+=32){
    #pragma unroll
    for (int rep=0;rep<4;rep++){
      int idx = tid + rep*256;
      int row = idx>>3, k4 = (idx&7)*4;
      int p = r0 + row;
      ushort4 st; st.x=0; st.y=0; st.z=0; st.w=0;
      if (p >= PADZ){
        float4 x = *(const float4*)(H + (size_t)(p - PADZ)*256 + k0 + k4);
        float mu = mus[row], rs = rss[row];
        st.x = f2bf((x.x-mu)*rs*gs[k0+k4+0] + bs2[k0+k4+0]);
        st.y = f2bf((x.y-mu)*rs*gs[k0+k4+1] + bs2[k0+k4+1]);
        st.z = f2bf((x.z-mu)*rs*gs[k0+k4+2] + bs2[k0+k4+2]);
        st.w = f2bf((x.w-mu)*rs*gs[k0+k4+3] + bs2[k0+k4+3]);
      }
      *(ushort4*)&As[row*40 + k4] = st;
    }
    #pragma unroll
    for (int rep=0;rep<2;rep++){
      int idx = tid + rep*256;
      int n = idx>>2, k8 = (idx&3)*8;
      uint4 wv = *(const uint4*)(WT + (size_t)(c0+n)*256 + k0 + k8);
      *(uint4*)&Bs[n*40 + k8] = wv;
    }
    __syncthreads();
    short8 af[4], bfr[4];
    #pragma unroll
    for (int i=0;i<4;i++) af[i]  = *(const short8*)&As[(wr*64 + i*16 + lm)*40 + q*8];
    #pragma unroll
    for (int j=0;j<4;j++) bfr[j] = *(const short8*)&Bs[(wc*64 + j*16 + lm)*40 + q*8];
    #pragma unroll
    for (int i=0;i<4;i++)
      #pragma unroll
      for (int j=0;j<4;j++)
        acc[i][j] = __builtin_amdgcn_mfma_f32_16x16x32_bf16(af[i], bfr[j], acc[i][j], 0,0,0);
    __syncthreads();
  }
  float scale = (blockIdx.y == 0) ? 0.17677669529663687f : 1.f;
  #pragma unroll
  for (int j=0;j<4;j++){
    int col = c0 + wc*64 + j*16 + lm;
    #pragma unroll
    for (int i=0;i<4;i++)
      #pragma unroll
      for (int reg=0;reg<4;reg++){
        int p = r0 + wr*64 + i*16 + q*4 + reg;
        QKV[(size_t)p*384 + col] = acc[i][j][reg]*scale;
      }
  }
}

// ---------------- out-proj: h[p-63] += OH @ W + b  (rows p>=63) ----------------
// grid (313,2).
__global__ __launch_bounds__(256) void k_projm(const float* __restrict__ OH, const u16* __restrict__ WT,
                                               const float* __restrict__ Bias, float* __restrict__ h){
  __shared__ __align__(16) u16 As[128*40];
  __shared__ __align__(16) u16 Bs[128*40];
  int tid = threadIdx.x;
  int r0 = blockIdx.x*128, c0 = blockIdx.y*128;
  int wid = tid>>6, lane = tid&63, lm = lane&15, q = lane>>4;
  int wr = wid>>1, wc = wid&1;
  floatx4 acc[4][4];
  #pragma unroll
  for (int i=0;i<4;i++)
    #pragma unroll
    for (int j=0;j<4;j++) acc[i][j] = (floatx4){0.f,0.f,0.f,0.f};
  for (int k0=0;k0<128;k0+=32){
    #pragma unroll
    for (int rep=0;rep<4;rep++){
      int idx = tid + rep*256;
      int row = idx>>3, k4 = (idx&7)*4;
      int p = r0 + row;
      float4 v = *(const float4*)(OH + (size_t)p*128 + k0 + k4);
      ushort4 st; st.x=f2bf(v.x); st.y=f2bf(v.y); st.z=f2bf(v.z); st.w=f2bf(v.w);
      *(ushort4*)&As[row*40 + k4] = st;
    }
    #pragma unroll
    for (int rep=0;rep<2;rep++){
      int idx = tid + rep*256;
      int n = idx>>2, k8 = (idx&3)*8;
      uint4 wv = *(const uint4*)(WT + (size_t)(c0+n)*128 + k0 + k8);
      *(uint4*)&Bs[n*40 + k8] = wv;
    }
    __syncthreads();
    short8 af[4], bfr[4];
    #pragma unroll
    for (int i=0;i<4;i++) af[i]  = *(const short8*)&As[(wr*64 + i*16 + lm)*40 + q*8];
    #pragma unroll
    for (int j=0;j<4;j++) bfr[j] = *(const short8*)&Bs[(wc*64 + j*16 + lm)*40 + q*8];
    #pragma unroll
    for (int i=0;i<4;i++)
      #pragma unroll
      for (int j=0;j<4;j++)
        acc[i][j] = __builtin_amdgcn_mfma_f32_16x16x32_bf16(af[i], bfr[j], acc[i][j], 0,0,0);
    __syncthreads();
  }
  #pragma unroll
  for (int j=0;j<4;j++){
    int col = c0 + wc*64 + j*16 + lm;
    float bj = Bias[col];
    #pragma unroll
    for (int i=0;i<4;i++)
      #pragma unroll
      for (int reg=0;reg<4;reg++){
        int p = r0 + wr*64 + i*16 + q*4 + reg;
        if (p >= PADZ){
          float* hp = h + (size_t)(p - PADZ)*256 + col;
          *hp += acc[i][j][reg] + bj;
        }
      }
  }
}

// ---------------- landmark means (atomic partial sums) ----------------
__global__ __launch_bounds__(256) void k_land(const float* __restrict__ QKV, float* __restrict__ QL,
                                              float* __restrict__ KL){
  int i = blockIdx.x, tc = blockIdx.y;
  int c = threadIdx.x;
  int t0 = tc*40;
  int nt = LCH - t0; if (nt > 40) nt = 40;
  const float* p = QKV + ((size_t)i*LCH + t0)*384 + c;
  float s0=0.f,s1=0.f,s2=0.f,s3=0.f;
  int t = 0;
  for (; t+4 <= nt; t += 4){
    s0 += p[(size_t)(t+0)*384];
    s1 += p[(size_t)(t+1)*384];
    s2 += p[(size_t)(t+2)*384];
    s3 += p[(size_t)(t+3)*384];
  }
  for (; t < nt; t++) s0 += p[(size_t)t*384];
  float s = ((s0+s1)+(s2+s3)) * (1.f/313.f);
  int hd = (c >> 5) & 3, d = c & 31;
  if (c < 128) atomicAdd(&QL[hd*4096 + i*32 + d], s);
  else         atomicAdd(&KL[hd*4096 + i*32 + d], s);
}

// ---------------- sim2 + row softmax -> A2 ----------------
__global__ __launch_bounds__(128) void k_sim2(const float* __restrict__ QL, const float* __restrict__ KL,
                                              float* __restrict__ A2){
  int h = blockIdx.y, i = blockIdx.x, j = threadIdx.x;
  __shared__ float q[32];
  __shared__ float red[2], red2[2];
  if (j < 32) q[j] = QL[h*4096 + i*32 + j];
  __syncthreads();
  const float* kr = KL + h*4096 + j*32;
  float s = 0.f;
  #pragma unroll
  for (int d=0;d<32;d++) s += q[d]*kr[d];
  float m = s;
  #pragma unroll
  for (int off=32; off; off>>=1) m = fmaxf(m, __shfl_xor(m, off));
  if ((j & 63) == 0) red[j>>6] = m;
  __syncthreads();
  m = fmaxf(red[0], red[1]);
  float p = __expf(fmaxf(s - m, -80.f));
  float sum = p;
  #pragma unroll
  for (int off=32; off; off>>=1) sum += __shfl_xor(sum, off);
  if ((j & 63) == 0) red2[j>>6] = sum;
  __syncthreads();
  sum = red2[0] + red2[1];
  A2[h*16384 + i*128 + j] = p / fmaxf(sum, 1e-30f);
}

// ---------------- scalar s = max(rowsum)*max(colsum) ----------------
__global__ __launch_bounds__(512) void k_colmax(const float* __restrict__ A2, float* __restrict__ S){
  int t = threadIdx.x;
  int h = t >> 7, j = t & 127;
  const float* base = A2 + h*16384;
  float cs = 0.f, rs = 0.f;
  #pragma unroll 4
  for (int i=0;i<128;i++){ cs += base[i*128 + j]; rs += base[j*128 + i]; }
  __shared__ float mc[8], mr[8];
  float c = cs, r = rs;
  #pragma unroll
  for (int off=32; off; off>>=1){ c = fmaxf(c, __shfl_xor(c,off)); r = fmaxf(r, __shfl_xor(r,off)); }
  int w = t >> 6;
  if ((t & 63) == 0){ mc[w] = c; mr[w] = r; }
  __syncthreads();
  if (t == 0){
    float M1 = mc[0], M2 = mr[0];
    for (int k=1;k<8;k++){ M1 = fmaxf(M1, mc[k]); M2 = fmaxf(M2, mr[k]); }
    S[0] = M1 * M2;
  }
}

// ---------------- z0 = A2^T / s ----------------
__global__ void k_z0(const float* __restrict__ A2, const float* __restrict__ S, float* __restrict__ Z){
  int idx = blockIdx.x*256 + threadIdx.x;
  float inv = 1.f / fmaxf(S[0], 1e-30f);
  int h = idx >> 14, rem = idx & 16383, i = rem >> 7, j = rem & 127;
  Z[h*16384 + j*128 + i] = A2[idx] * inv;
}

// ---------------- batched 128x128: C[h] = alpha*A[h]@B[h] + beta*A[h] ----------------
__global__ __launch_bounds__(256) void k_bmm(const float* __restrict__ A, const float* __restrict__ B,
                                             float* __restrict__ C, float alpha, float beta){
  __shared__ float As[16][132];
  __shared__ float Bs[128][64];
  int h = blockIdx.y;
  int r0 = (blockIdx.x & 7) * 16, cb = (blockIdx.x >> 3) * 64;
  const float* Ah = A + h*16384;
  const float* Bh = B + h*16384;
  int tid = threadIdx.x;
  #pragma unroll
  for (int rep=0;rep<8;rep++){
    int i = tid + rep*256;
    int r = i >> 7, k = i & 127;
    As[r][k] = Ah[(r0 + r)*128 + k];
  }
  #pragma unroll
  for (int rep=0;rep<32;rep++){
    int i = tid + rep*256;
    int k = i >> 6, c = i & 63;
    Bs[k][c] = Bh[k*128 + cb + c];
  }
  __syncthreads();
  int r = tid >> 4, c0 = (tid & 15) * 4;
  float4 acc; acc.x=0.f; acc.y=0.f; acc.z=0.f; acc.w=0.f;
  for (int k4=0;k4<128;k4+=4){
    float4 a = *(const float4*)&As[r][k4];
    float aa[4] = {a.x,a.y,a.z,a.w};
    #pragma unroll
    for (int kk=0;kk<4;kk++){
      float4 b = *(const float4*)&Bs[k4+kk][c0];
      acc.x += aa[kk]*b.x; acc.y += aa[kk]*b.y; acc.z += aa[kk]*b.z; acc.w += aa[kk]*b.w;
    }
  }
  float4 av = *(const float4*)&As[r][cb + c0];
  float4 o;
  o.x = fminf(fmaxf(alpha*acc.x + beta*av.x, -1e20f), 1e20f);
  o.y = fminf(fmaxf(alpha*acc.y + beta*av.y, -1e20f), 1e20f);
  o.z = fminf(fmaxf(alpha*acc.z + beta*av.z, -1e20f), 1e20f);
  o.w = fminf(fmaxf(alpha*acc.w + beta*av.w, -1e20f), 1e20f);
  *(float4*)(C + h*16384 + (r0 + r)*128 + cb + c0) = o;
}

// ---------------- max squared norms for softmax bound ----------------
__global__ __launch_bounds__(256) void k_normk(const float* __restrict__ QKV, float* __restrict__ KN2){
  int tid = threadIdx.x;
  int row = blockIdx.x*64 + (tid >> 2);
  int h = tid & 3;
  const float* v = QKV + (size_t)row*384 + 128 + h*32;
  float n2 = 0.f;
  #pragma unroll
  for (int d=0;d<32;d+=4){ float4 x = *(const float4*)(v+d); n2 += x.x*x.x+x.y*x.y+x.z*x.z+x.w*x.w; }
  #pragma unroll
  for (int off=4; off<64; off<<=1) n2 = fmaxf(n2, __shfl_xor(n2, off));
  __shared__ float red[4][4];
  int lane = tid & 63, w = tid >> 6;
  if (lane < 4) red[w][lane] = n2;
  __syncthreads();
  if (tid < 4){
    float m = fmaxf(fmaxf(red[0][tid], red[1][tid]), fmaxf(red[2][tid], red[3][tid]));
    atomicMax((unsigned*)&KN2[tid], __float_as_uint(m));
  }
}

__global__ __launch_bounds__(256) void k_normq(const float* __restrict__ QL, float* __restrict__ QN2){
  int tid = threadIdx.x;
  #pragma unroll
  for (int rep=0; rep<2; rep++){
    int row = tid + rep*256;
    int h = row >> 7;
    const float* q = QL + row*32;
    float n2 = 0.f;
    #pragma unroll
    for (int d=0;d<32;d+=4){ float4 x = *(const float4*)(q+d); n2 += x.x*x.x+x.y*x.y+x.z*x.z+x.w*x.w; }
    atomicMax((unsigned*)&QN2[h], __float_as_uint(n2));
  }
}

// ---------------- flash sim3 ----------------
__global__ __launch_bounds__(256) void k_flash(const float* __restrict__ QKV, const float* __restrict__ QL,
                                               const float* __restrict__ KN2, const float* __restrict__ QN2,
                                               float* __restrict__ LPART, float* __restrict__ OPART){
  __shared__ union UU {
    struct { float Qt[32][132]; float Kt[32][132]; } a;
    u16 PsT[128][132];
  } U;
  __shared__ float Vs[128][36];
  int h = blockIdx.y, ci = blockIdx.x;
  int k0 = ci * 128;
  int tid = threadIdx.x;
  int tx = tid & 15, ty = tid >> 4;
  #pragma unroll
  for (int rep=0;rep<16;rep++){
    int i = tid + rep*256;
    int q = i >> 5, d = i & 31;
    U.a.Qt[d][q] = QL[h*4096 + i];
  }
  #pragma unroll
  for (int rep=0;rep<16;rep++){
    int i = tid + rep*256;
    int kk = i >> 5, d = i & 31;
    U.a.Kt[d][kk] = QKV[(size_t)(k0+kk)*384 + 128 + h*32 + d];
    Vs[kk][d]     = QKV[(size_t)(k0+kk)*384 + 256 + h*32 + d];
  }
  __syncthreads();
  float bound = sqrtf(KN2[h]*QN2[h]) + 1e-6f;
  float s[8][8];
  #pragma unroll
  for (int i=0;i<8;i++)
    #pragma unroll
    for (int c=0;c<8;c++) s[i][c]=0.f;
  for (int d=0;d<32;d++){
    float4 qa = *(const float4*)&U.a.Qt[d][ty*8];
    float4 qb = *(const float4*)&U.a.Qt[d][ty*8+4];
    float4 ka = *(const float4*)&U.a.Kt[d][tx*8];
    float4 kb = *(const float4*)&U.a.Kt[d][tx*8+4];
    float qv[8] = {qa.x,qa.y,qa.z,qa.w,qb.x,qb.y,qb.z,qb.w};
    float kv[8] = {ka.x,ka.y,ka.z,ka.w,kb.x,kb.y,kb.z,kb.w};
    #pragma unroll
    for (int i=0;i<8;i++)
      #pragma unroll
      for (int c=0;c<8;c++) s[i][c] += qv[i]*kv[c];
  }
  float l[8];
  #pragma unroll
  for (int i=0;i<8;i++){
    float li = 0.f;
    #pragma unroll
    for (int c=0;c<8;c++){ s[i][c] = __expf(fmaxf(s[i][c] - bound, -80.f)); li += s[i][c]; }
    l[i] = li;
  }
  #pragma unroll
  for (int off=1; off<16; off<<=1)
    #pragma unroll
    for (int i=0;i<8;i++) l[i] += __shfl_xor(l[i], off);
  if (tx == 0){
    #pragma unroll
    for (int i=0;i<8;i++) LPART[(size_t)(h*313 + ci)*128 + ty*8 + i] = l[i];
  }
  __syncthreads();
  #pragma unroll
  for (int i=0;i<8;i++)
    #pragma unroll
    for (int c=0;c<8;c++) U.PsT[tx*8+c][ty*8+i] = f2bf(s[i][c]);
  __syncthreads();
  int txp = tx & 7, kh = (tx >> 3)*64;
  float o[8][4];
  #pragma unroll
  for (int i=0;i<8;i++)
    #pragma unroll
    for (int c=0;c<4;c++) o[i][c]=0.f;
  for (int k=0;k<64;k++){
    const u16* pr = &U.PsT[kh + k][ty*8];
    ushort4 pa = *(const ushort4*)pr;
    ushort4 pb = *(const ushort4*)(pr+4);
    float4 vv = *(const float4*)&Vs[kh + k][txp*4];
    float pv[8] = {bf2f(pa.x),bf2f(pa.y),bf2f(pa.z),bf2f(pa.w),
                   bf2f(pb.x),bf2f(pb.y),bf2f(pb.z),bf2f(pb.w)};
    float vd[4] = {vv.x,vv.y,vv.z,vv.w};
    #pragma unroll
    for (int i=0;i<8;i++)
      #pragma unroll
      for (int c=0;c<4;c++) o[i][c] += pv[i]*vd[c];
  }
  #pragma unroll
  for (int i=0;i<8;i++)
    #pragma unroll
    for (int c=0;c<4;c++) o[i][c] += __shfl_xor(o[i][c], 8);
  if (tx < 8){
    size_t base = ((size_t)(h*313 + ci)*128)*32;
    #pragma unroll
    for (int i=0;i<8;i++){
      float4 st; st.x=o[i][0]; st.y=o[i][1]; st.z=o[i][2]; st.w=o[i][3];
      *(float4*)(OPART + base + (size_t)(ty*8+i)*32 + txp*4) = st;
    }
  }
}

// ---------------- reduce flash partials ----------------
__global__ __launch_bounds__(256) void k_fred(const float* __restrict__ OPART, float* __restrict__ ACC){
  int h = blockIdx.y;
  int off = blockIdx.x*256 + threadIdx.x;
  const float* p = OPART + (size_t)h*1282048 + off;
  float s0=0.f,s1=0.f,s2=0.f,s3=0.f;
  int ci=0;
  for (; ci+4<=313; ci+=4){
    s0 += p[(size_t)(ci+0)*4096];
    s1 += p[(size_t)(ci+1)*4096];
    s2 += p[(size_t)(ci+2)*4096];
    s3 += p[(size_t)(ci+3)*4096];
  }
  for (; ci<313; ci++) s0 += p[(size_t)ci*4096];
  ACC[h*4096 + off] = (s0+s1)+(s2+s3);
}

__global__ void k_lred(const float* __restrict__ LPART, float* __restrict__ LAC){
  int idx = blockIdx.x*256 + threadIdx.x;
  int h = idx >> 7, j = idx & 127;
  const float* p = LPART + (size_t)(h*313)*128 + j;
  float s0=0.f,s1=0.f;
  int ci=0;
  for (; ci+2<=313; ci+=2){ s0 += p[(size_t)(ci+0)*128]; s1 += p[(size_t)(ci+1)*128]; }
  for (; ci<313; ci++) s0 += p[(size_t)ci*128];
  LAC[idx] = s0+s1;
}

// ---------------- W = Z @ t3 ----------------
__global__ __launch_bounds__(256) void k_w(const float* __restrict__ Z, const float* __restrict__ ACC,
                                           const float* __restrict__ LAC, float* __restrict__ WB){
  int h = blockIdx.x;
  __shared__ float t3s[128][33];
  int tid = threadIdx.x;
  #pragma unroll
  for (int rep=0; rep<16; rep++){
    int i = tid + rep*256;
    int j = i >> 5, d = i & 31;
    float t3 = ACC[h*4096 + i] / fmaxf(LAC[h*128 + j], 1e-30f);
    t3s[j][d] = fminf(fmaxf(t3, -1e20f), 1e20f);
  }
  __syncthreads();
  int i = tid >> 1, dh = (tid & 1)*16;
  float acc[16];
  #pragma unroll
  for (int d=0;d<16;d++) acc[d]=0.f;
  const float* zr = Z + h*16384 + i*128;
  for (int j=0;j<128;j++){
    float zv = zr[j];
    #pragma unroll
    for (int d=0;d<16;d++) acc[d] += zv * t3s[j][dh + d];
  }
  float* w = WB + h*4096 + i*32 + dh;
  #pragma unroll
  for (int d=0;d<16;d+=4){
    float4 st;
    st.x = fminf(fmaxf(acc[d+0], -1e20f), 1e20f);
    st.y = fminf(fmaxf(acc[d+1], -1e20f), 1e20f);
    st.z = fminf(fmaxf(acc[d+2], -1e20f), 1e20f);
    st.w = fminf(fmaxf(acc[d+3], -1e20f), 1e20f);
    *(float4*)(w+d) = st;
  }
}

// ---------------- sim1: OH = softmax(Q KL^T) @ W ----------------
__global__ __launch_bounds__(256) void k_sim1(const float* __restrict__ QKV, const float* __restrict__ KL,
                                              const float* __restrict__ WB, float* __restrict__ OH){
  __shared__ union UU {
    struct { float Qt[32][68]; float KLt[32][132]; } a;
    float PsT[128][68];
  } U;
  __shared__ float ws[128][36];
  int h = blockIdx.y;
  int p0 = blockIdx.x * 64;
  int tid = threadIdx.x;
  int tx = tid & 15, ty = tid >> 4;
  #pragma unroll
  for (int rep=0;rep<8;rep++){
    int i = tid + rep*256;
    int t = i >> 5, d = i & 31;
    U.a.Qt[d][t] = QKV[(size_t)(p0 + t)*384 + h*32 + d];
  }
  #pragma unroll
  for (int rep=0;rep<16;rep++){
    int i = tid + rep*256;
    int j = i >> 5, d = i & 31;
    U.a.KLt[d][j] = KL[h*4096 + i];
    ws[j][d] = WB[h*4096 + i];
  }
  __syncthreads();
  float s[4][8];
  #pragma unroll
  for (int i=0;i<4;i++)
    #pragma unroll
    for (int c=0;c<8;c++) s[i][c]=0.f;
  for (int d=0;d<32;d++){
    float4 qa = *(const float4*)&U.a.Qt[d][ty*4];
    float4 ka = *(const float4*)&U.a.KLt[d][tx*4];
    float4 kb = *(const float4*)&U.a.KLt[d][64 + tx*4];
    float qv[4] = {qa.x,qa.y,qa.z,qa.w};
    float kv[8] = {ka.x,ka.y,ka.z,ka.w,kb.x,kb.y,kb.z,kb.w};
    #pragma unroll
    for (int i=0;i<4;i++)
      #pragma unroll
      for (int c=0;c<8;c++) s[i][c] += qv[i]*kv[c];
  }
  float m[4], l[4];
  #pragma unroll
  for (int i=0;i<4;i++){
    float mi = s[i][0];
    #pragma unroll
    for (int c=1;c<8;c++) mi = fmaxf(mi, s[i][c]);
    m[i] = mi;
  }
  #pragma unroll
  for (int off=1; off<16; off<<=1)
    #pragma unroll
    for (int i=0;i<4;i++) m[i] = fmaxf(m[i], __shfl_xor(m[i], off));
  #pragma unroll
  for (int i=0;i<4;i++){
    float li = 0.f;
    #pragma unroll
    for (int c=0;c<8;c++){ s[i][c] = __expf(fmaxf(s[i][c] - m[i], -80.f)); li += s[i][c]; }
    l[i] = li;
  }
  #pragma unroll
  for (int off=1; off<16; off<<=1)
    #pragma unroll
    for (int i=0;i<4;i++) l[i] += __shfl_xor(l[i], off);
  #pragma unroll
  for (int i=0;i<4;i++){
    float inv = 1.f / fmaxf(l[i], 1e-30f);
    #pragma unroll
    for (int c=0;c<8;c++) s[i][c] *= inv;
  }
  __syncthreads();
  #pragma unroll
  for (int i=0;i<4;i++)
    #pragma unroll
    for (int c=0;c<8;c++){
      int j = (c>>2)*64 + tx*4 + (c&3);
      U.PsT[j][ty*4 + i] = s[i][c];
    }
  __syncthreads();
  int txp = tx & 7, jh = (tx >> 3)*64;
  float o[4][4];
  #pragma unroll
  for (int i=0;i<4;i++)
    #pragma unroll
    for (int c=0;c<4;c++) o[i][c]=0.f;
  for (int j=0;j<64;j++){
    float4 pv = *(const float4*)&U.PsT[jh + j][ty*4];
    float4 wv = *(const float4*)&ws[jh + j][txp*4];
    float pa[4] = {pv.x,pv.y,pv.z,pv.w};
    float wa[4] = {wv.x,wv.y,wv.z,wv.w};
    #pragma unroll
    for (int i=0;i<4;i++)
      #pragma unroll
      for (int c=0;c<4;c++) o[i][c] += pa[i]*wa[c];
  }
  #pragma unroll
  for (int i=0;i<4;i++)
    #pragma unroll
    for (int c=0;c<4;c++) o[i][c] += __shfl_xor(o[i][c], 8);
  if (tx < 8){
    #pragma unroll
    for (int i=0;i<4;i++){
      float4 st; st.x=o[i][0]; st.y=o[i][1]; st.z=o[i][2]; st.w=o[i][3];
      *(float4*)(OH + (size_t)(p0 + ty*4 + i)*128 + h*32 + txp*4) = st;
    }
  }
}

// ---------------- depthwise 33x1 conv residual on V ----------------
__global__ __launch_bounds__(256) void k_res(const float* __restrict__ QKV, const float* __restrict__ RK,
                                             float* __restrict__ OH){
  __shared__ float vs[96][128];
  __shared__ float rks[132];
  int p0 = blockIdx.x * 64;
  int tid = threadIdx.x;
  #pragma unroll
  for (int rep=0;rep<48;rep++){
    int i = tid + rep*256;
    int lr = i >> 7, c = i & 127;
    int row = p0 - 16 + lr;
    float v = 0.f;
    if (row >= 0 && row < NPAD) v = QKV[(size_t)row*384 + 256 + c];
    vs[lr][c] = v;
  }
  if (tid < 132) rks[tid] = RK[tid];
  __syncthreads();
  int c = tid & 127, rb = (tid >> 7)*32;
  int hh = c >> 5;
  const float* rk = &rks[hh*33];
  for (int k=0;k<32;k++){
    int r = rb + k;
    float acc = 0.f;
    #pragma unroll
    for (int t=0;t<33;t++) acc += vs[r + t][c] * rk[t];
    OH[(size_t)(p0 + r)*128 + c] += acc;
  }
}

// ---------------- depthwise 7x7+5x5+3x3 convs ----------------
__global__ __launch_bounds__(256) void k_dw(const float* __restrict__ h,
                                            const float* __restrict__ W7, const float* __restrict__ B7,
                                            const float* __restrict__ W5, const float* __restrict__ B5,
                                            const float* __restrict__ W3, const float* __restrict__ B3,
                                            float* __restrict__ out){
  __shared__ float img[196][32];
  __shared__ float w7s[49][32], w5s[25][32], w3s[9][32];
  __shared__ float bs[32];
  int bx = blockIdx.x, by = blockIdx.y;
  int c0 = blockIdx.z * 32;
  int tid = threadIdx.x;
  int gx0 = bx*8 - 3, gy0 = by*8 - 3;
  for (int rep=0; rep<25; rep++){
    int i = tid + rep*256;
    if (i < 6272){
      int pos = i >> 5, c = i & 31;
      int ly = pos / 14, lx = pos - ly*14;
      int gy = gy0 + ly, gx = gx0 + lx;
      float v = 0.f;
      if (gy >= 0 && gy < SIDE && gx >= 0 && gx < SIDE)
        v = h[(size_t)(1 + gy*SIDE + gx)*256 + c0 + c];
      img[pos][c] = v;
    }
  }
  for (int rep=0; rep<7; rep++){
    int i = tid + rep*256;
    if (i < 1568){ int t = i >> 5, c = i & 31; w7s[t][c] = W7[(size_t)(c0 + c)*49 + t]; }
  }
  for (int rep=0; rep<4; rep++){
    int i = tid + rep*256;
    if (i < 800){ int t = i >> 5, c = i & 31; w5s[t][c] = W5[(size_t)(c0 + c)*25 + t]; }
  }
  for (int rep=0; rep<2; rep++){
    int i = tid + rep*256;
    if (i < 288){ int t = i >> 5, c = i & 31; w3s[t][c] = W3[(size_t)(c0 + c)*9 + t]; }
  }
  if (tid < 32) bs[tid] = B7[c0+tid] + B5[c0+tid] + B3[c0+tid];
  __syncthreads();
  int c = tid & 31, pg = tid >> 5;
  float acc[8];
  #pragma unroll
  for (int px=0; px<8; px++) acc[px] = img[(pg+3)*14 + px+3][c] + bs[c];
  for (int t=0;t<49;t++){
    float wv = w7s[t][c];
    int dy = t/7, dx = t - dy*7;
    #pragma unroll
    for (int px=0;px<8;px++) acc[px] += img[(pg+dy)*14 + px+dx][c]*wv;
  }
  for (int t=0;t<25;t++){
    float wv = w5s[t][c];
    int dy = t/5, dx = t - dy*5;
    #pragma unroll
    for (int px=0;px<8;px++) acc[px] += img[(pg+1+dy)*14 + px+1+dx][c]*wv;
  }
  for (int t=0;t<9;t++){
    float wv = w3s[t][c];
    int dy = t/3, dx = t - dy*3;
    #pragma unroll
    for (int px=0;px<8;px++) acc[px] += img[(pg+2+dy)*14 + px+2+dx][c]*wv;
  }
  int gy = by*8 + pg;
  #pragma unroll
  for (int px=0;px<8;px++){
    int gxp = bx*8 + px;
    out[(size_t)(gy*SIDE + gxp)*256 + c0 + c] = acc[px];
  }
}

__global__ void k_copyback(const float* __restrict__ temp, float* __restrict__ h){
  int i = blockIdx.x*256 + threadIdx.x;
  float4 v = ((const float4*)temp)[i];
  ((float4*)(h + 256))[i] = v;
}

// ---------------- final LN(row0) @ fc2 + b ----------------
__global__ __launch_bounds__(256) void k_final(const float* __restrict__ h, const float* __restrict__ g,
                                               const float* __restrict__ b, const float* __restrict__ W2,
                                               const float* __restrict__ B2, float* __restrict__ out){
  __shared__ float red[4], red2[4];
  __shared__ float hn[256];
  int tid = threadIdx.x;
  float x = h[tid];
  float s = x, sq = x*x;
  #pragma unroll
  for (int off=32; off; off>>=1){ s += __shfl_xor(s,off); sq += __shfl_xor(sq,off); }
  int w = tid >> 6;
  if ((tid & 63) == 0){ red[w] = s; red2[w] = sq; }
  __syncthreads();
  s = red[0]+red[1]+red[2]+red[3];
  sq = red2[0]+red2[1]+red2[2]+red2[3];
  float mu = s*(1.f/256.f);
  float var = sq*(1.f/256.f) - mu*mu;
  float rstd = rsqrtf(fmaxf(var, 0.f) + 1e-5f);
  hn[tid] = (x - mu)*rstd*g[tid] + b[tid];
  __syncthreads();
  if (tid < 4){
    float acc = B2[tid];
    for (int c=0;c<256;c++) acc += hn[c]*W2[c*4 + tid];
    out[tid] = acc;
  }
}

// ================= host side =================
struct Bufs {
  float *HB, *QKV, *OH, *LP, *QL, *KL, *WB, *A2, *ZB0, *ZB1, *PB, *T1B, *T2B, *SB, *KN2, *QN2, *LAC, *ACC;
  u16 *WT1, *WTQ1, *WTQ2, *WTO1, *WTO2;
};

static void attention(const Bufs& B, const u16* qkv_wt, const u16* out_wt, const float* out_b,
                      const float* res_k, const float* ln_g, const float* ln_b, hipStream_t stream){
  k_qkvm<<<dim3(313,3),256,0,stream>>>(B.HB, ln_g, ln_b, qkv_wt, B.QKV);
  k_zero<<<128,256,0,stream>>>(B.QL, 32768);
  k_land<<<dim3(128,8),256,0,stream>>>(B.QKV, B.QL, B.KL);
  k_sim2<<<dim3(128,4),128,0,stream>>>(B.QL, B.KL, B.A2);
  k_colmax<<<1,512,0,stream>>>(B.A2, B.SB);
  k_z0<<<256,256,0,stream>>>(B.A2, B.SB, B.ZB0);
  float* zin = B.ZB0; float* zout = B.ZB1;
  for (int it=0; it<6; it++){
    k_bmm<<<dim3(16,4),256,0,stream>>>(B.A2, zin, B.PB, 1.f, 0.f);
    k_bmm<<<dim3(16,4),256,0,stream>>>(B.PB, B.PB, B.T1B, -1.f, 7.f);
    k_bmm<<<dim3(16,4),256,0,stream>>>(B.PB, B.T1B, B.T2B, -1.f, 15.f);
    k_bmm<<<dim3(16,4),256,0,stream>>>(zin, B.T2B, zout, -0.25f, 3.25f);
    float* t = zin; zin = zout; zout = t;
  }
  k_zero<<<1,256,0,stream>>>(B.KN2, 8);
  k_normk<<<626,256,0,stream>>>(B.QKV, B.KN2);
  k_normq<<<1,256,0,stream>>>(B.QL, B.QN2);
  k_flash<<<dim3(313,4),256,0,stream>>>(B.QKV, B.QL, B.KN2, B.QN2, B.LP, B.OH);
  k_fred<<<dim3(16,4),256,0,stream>>>(B.OH, B.ACC);
  k_lred<<<2,256,0,stream>>>(B.LP, B.LAC);
  k_w<<<4,256,0,stream>>>(zin, B.ACC, B.LAC, B.WB);
  k_sim1<<<dim3(626,4),256,0,stream>>>(B.QKV, B.KL, B.WB, B.OH);
  k_res<<<626,256,0,stream>>>(B.QKV, res_k, B.OH);
  k_projm<<<dim3(313,2),256,0,stream>>>(B.OH, out_wt, out_b, B.HB);
}

extern "C" void kernel_launch(void* const* d_in, const int* in_sizes, int n_in,
                              void* d_out, int out_size, void* d_ws, size_t ws_size,
                              hipStream_t stream){
  (void)in_sizes; (void)n_in; (void)out_size; (void)ws_size;
  const float* x_path = (const float*)d_in[0];
  const float* fc1_w  = (const float*)d_in[1];
  const float* fc1_b  = (const float*)d_in[2];
  const float* cls    = (const float*)d_in[3];
  const float* ln1_g  = (const float*)d_in[4];
  const float* ln1_b  = (const float*)d_in[5];
  const float* qkv1_w = (const float*)d_in[6];
  const float* out1_w = (const float*)d_in[7];
  const float* out1_b = (const float*)d_in[8];
  const float* res1_k = (const float*)d_in[9];
  const float* p7_w = (const float*)d_in[10];
  const float* p7_b = (const float*)d_in[11];
  const float* p5_w = (const float*)d_in[12];
  const float* p5_b = (const float*)d_in[13];
  const float* p3_w = (const float*)d_in[14];
  const float* p3_b = (const float*)d_in[15];
  const float* ln2_g  = (const float*)d_in[16];
  const float* ln2_b  = (const float*)d_in[17];
  const float* qkv2_w = (const float*)d_in[18];
  const float* out2_w = (const float*)d_in[19];
  const float* out2_b = (const float*)d_in[20];
  const float* res2_k = (const float*)d_in[21];
  const float* lnf_g  = (const float*)d_in[22];
  const float* lnf_b  = (const float*)d_in[23];
  const float* fc2_w  = (const float*)d_in[24];
  const float* fc2_b  = (const float*)d_in[25];

  float* ws = (float*)d_ws;
  Bufs B;
  B.QL  = ws;
  B.KL  = B.QL  + 16384;
  B.WB  = B.KL  + 16384;
  B.A2  = B.WB  + 16384;
  B.ZB0 = B.A2  + 65536;
  B.ZB1 = B.ZB0 + 65536;
  B.PB  = B.ZB1 + 65536;
  B.T1B = B.PB  + 65536;
  B.T2B = B.T1B + 65536;
  B.SB  = B.T2B + 65536;
  B.KN2 = B.SB  + 16;
  B.QN2 = B.KN2 + 4;
  B.LAC = B.QN2 + 4;
  B.ACC = B.LAC + 512;
  B.LP  = B.ACC + 16384;
  B.OH  = B.LP  + 160256;
  B.HB  = B.OH  + 5128192;
  B.QKV = B.HB  + 10240256;
  // bf16 transposed weights (16B-aligned: float offset is a multiple of 4)
  B.WT1  = (u16*)(B.QKV + 15384576);        // 256x1024
  B.WTQ1 = B.WT1  + 262144;                 // 384x256
  B.WTQ2 = B.WTQ1 + 98304;                  // 384x256
  B.WTO1 = B.WTQ2 + 98304;                  // 256x128
  B.WTO2 = B.WTO1 + 32768;                  // 256x128

  k_transp<<<1024,256,0,stream>>>(fc1_w,  B.WT1,  1024, 256);
  k_transp<<< 384,256,0,stream>>>(qkv1_w, B.WTQ1,  256, 384);
  k_transp<<< 384,256,0,stream>>>(qkv2_w, B.WTQ2,  256, 384);
  k_transp<<< 128,256,0,stream>>>(out1_w, B.WTO1,  128, 256);
  k_transp<<< 128,256,0,stream>>>(out2_w, B.WTO2,  128, 256);

  k_cls<<<1,256,0,stream>>>(cls, B.HB);
  k_fc1m<<<dim3(313,2),256,0,stream>>>(x_path, B.WT1, fc1_b, B.HB);

  attention(B, B.WTQ1, B.WTO1, out1_b, res1_k, ln1_g, ln1_b, stream);

  k_dw<<<dim3(25,25,8),256,0,stream>>>(B.HB, p7_w,p7_b, p5_w,p5_b, p3_w,p3_b, B.QKV);
  k_copyback<<<10000,256,0,stream>>>(B.QKV, B.HB);

  attention(B, B.WTQ2, B.WTO2, out2_b, res2_k, ln2_g, ln2_b, stream);

  k_final<<<1,256,0,stream>>>(B.HB, lnf_g, lnf_b, fc2_w, fc2_b, (float*)d_out);
}